// Round 19
// baseline (142.265 us; speedup 1.0000x reference)
//
#include <hip/hip_runtime.h>
#include <math.h>

// VimBlock: B=32, J=1024, D=192, E=384, N=16, K=3.
// MFMA bf16; XCD-affinity swizzle everywhere (rb=(row/64)%8 -> bid%8).
// R19: final split into two single-GEMM streaming kernels (yr_gemm, out_gemm).

typedef __attribute__((ext_vector_type(8))) short short8;
typedef __attribute__((ext_vector_type(4))) float f32x4;

__device__ __forceinline__ unsigned short f2bf(float f){
  union { float f; unsigned u; } v; v.f = f;
  unsigned r = v.u + 0x7FFFu + ((v.u >> 16) & 1u);   // RNE
  return (unsigned short)(r >> 16);
}
__device__ __forceinline__ float bf2f(unsigned short s){
  union { unsigned u; float f; } v; v.u = ((unsigned)s) << 16;
  return v.f;
}
__device__ __forceinline__ float softplusf(float x){
  return (x > 20.f) ? x : log1pf(expf(x));
}
__device__ __forceinline__ float softplus_fast(float x){
  return (x > 20.f) ? x : __logf(1.f + __expf(x));
}
__device__ __forceinline__ float sigf_fast(float x){
  return __builtin_amdgcn_rcpf(1.f + __expf(-x));
}

// ---------------- prep: pack weights to bf16 transposed layouts ----------------
__global__ __launch_bounds__(256) void prep_kernel(
    const float* __restrict__ Wx, const float* __restrict__ Wz,
    const float* __restrict__ WBf, const float* __restrict__ WCf,
    const float* __restrict__ WDf, const float* __restrict__ WBb,
    const float* __restrict__ WCb, const float* __restrict__ WDb,
    const float* __restrict__ Wi, const float* __restrict__ Wr,
    const float* __restrict__ Wo,
    const float* __restrict__ bBf, const float* __restrict__ bCf,
    const float* __restrict__ bDf, const float* __restrict__ bBb,
    const float* __restrict__ bCb, const float* __restrict__ bDb,
    const float* __restrict__ bi,
    unsigned short* __restrict__ Wxz_t, unsigned short* __restrict__ W4f_t,
    unsigned short* __restrict__ W4b_t, unsigned short* __restrict__ Wrt2,
    unsigned short* __restrict__ Wot, float* __restrict__ b4f,
    float* __restrict__ b4b)
{
  int idx = blockIdx.x * 256 + threadIdx.x;
  if (idx < 147456){ int n = idx / 192, k = idx % 192;
    Wxz_t[idx] = f2bf(n < 384 ? Wx[k*384 + n] : Wz[k*384 + n - 384]); return; }
  idx -= 147456;
  if (idx < 24576){ int n = idx / 384, k = idx % 384;
    const float* W = (n<16)?WBf:(n<32)?WCf:(n<48)?WDf:Wi;
    W4f_t[idx] = f2bf(W[k*16 + (n&15)]); return; }
  idx -= 24576;
  if (idx < 24576){ int n = idx / 384, k = idx % 384;
    const float* W = (n<16)?WBb:(n<32)?WCb:(n<48)?WDb:Wi;
    W4b_t[idx] = f2bf(W[k*16 + (n&15)]); return; }
  idx -= 24576;
  if (idx < 12288){ int n = idx / 32, k = idx % 32;
    Wrt2[idx] = f2bf(Wr[(k&15)*384 + n]); return; }
  idx -= 12288;
  if (idx < 73728){ int n = idx / 384, k = idx % 384;
    Wot[idx] = f2bf(Wo[k*192 + n]); return; }
  idx -= 73728;
  if (idx < 64){
    const float* bsel = (idx<16)?bBf:(idx<32)?bCf:(idx<48)?bDf:bi;
    b4f[idx] = bsel[idx & 15]; return; }
  idx -= 64;
  if (idx < 64){
    const float* bsel = (idx<16)?bBb:(idx<32)?bCb:(idx<48)?bDb:bi;
    b4b[idx] = bsel[idx & 15]; return; }
}

// ---------------- Stage A1: LayerNorm -> t_bf ----------------
__global__ __launch_bounds__(256) void ln_kernel(
    const float* __restrict__ tokens, const float* __restrict__ g,
    const float* __restrict__ nb, unsigned short* __restrict__ t_bf)
{
  __shared__ unsigned short s[32 * 200];
  const int t = threadIdx.x;
  const int bid = blockIdx.x;
  const int a = bid >> 4, x = bid & 7, h = (bid >> 3) & 1;
  const int v = a*8 + x;
  const int row0 = (v*2 + h) * 32;
  {
    const int r = t >> 3, l8 = t & 7;
    const float* tr = tokens + (long)(row0 + r) * 192;
    float vv[24], sm = 0.f, sq = 0.f;
#pragma unroll
    for (int i = 0; i < 24; i++){ float xx = tr[l8 + 8*i]; vv[i] = xx; sm += xx; sq += xx*xx; }
#pragma unroll
    for (int m = 1; m < 8; m <<= 1){ sm += __shfl_xor(sm, m); sq += __shfl_xor(sq, m); }
    const float mu = sm * (1.f/192.f);
    const float rstd = rsqrtf(sq * (1.f/192.f) - mu*mu + 1e-5f);
#pragma unroll
    for (int i = 0; i < 24; i++){
      const int d = l8 + 8*i;
      s[r*200 + d] = f2bf((vv[i] - mu)*rstd*g[d] + nb[d]);
    }
  }
  __syncthreads();
  {
#pragma unroll
    for (int i = 0; i < 3; i++){
      const int item = i*256 + t;
      const int row = item / 24, c8 = item % 24;
      *(short8*)&t_bf[(long)(row0 + row)*192 + c8*8] =
          *(const short8*)&s[row*200 + c8*8];
    }
  }
}

// ---------------- Stage A2: streaming GEMM t_bf @ Wxz -> x_bf / gate_bf ----------------
__global__ __launch_bounds__(256) void xz_gemm(
    const unsigned short* __restrict__ t_bf,
    const unsigned short* __restrict__ Wxz_t,
    const float* __restrict__ bx, const float* __restrict__ bz,
    unsigned short* __restrict__ x_bf, unsigned short* __restrict__ gate_bf)
{
  __shared__ unsigned short tl[64 * 200];
  const int t = threadIdx.x;
  const int bid = blockIdx.x;
  const int a = bid / 48, rem = bid % 48;
  const int ct = rem >> 3;
  const int rt = a*8 + (rem & 7);
  const int row0 = rt * 64;

  {
#pragma unroll
    for (int i = 0; i < 6; i++){
      const int item = i*256 + t;
      const int row = item / 24, c8 = item % 24;
      *(short8*)&tl[row*200 + c8*8] =
          *(const short8*)&t_bf[(long)(row0 + row)*192 + c8*8];
    }
  }
  __syncthreads();

  const int lane = t & 63, w = t >> 6;
  const int l15 = lane & 15, q = lane >> 4;
  const int C0 = ct*128 + w*32;

  f32x4 acc[4][2];
#pragma unroll
  for (int m = 0; m < 4; m++)
#pragma unroll
    for (int nf = 0; nf < 2; nf++) acc[m][nf] = (f32x4){0.f,0.f,0.f,0.f};

  const unsigned short* wb = Wxz_t + (long)(C0 + l15)*192 + q*8;
#pragma unroll
  for (int ks = 0; ks < 6; ks++){
    const int k0 = ks * 32;
    short8 a0 = *(const short8*)&tl[(     l15)*200 + k0 + q*8];
    short8 a1 = *(const short8*)&tl[(16 + l15)*200 + k0 + q*8];
    short8 a2 = *(const short8*)&tl[(32 + l15)*200 + k0 + q*8];
    short8 a3 = *(const short8*)&tl[(48 + l15)*200 + k0 + q*8];
#pragma unroll
    for (int nf = 0; nf < 2; nf++){
      short8 bw = *(const short8*)&wb[nf*16*192 + k0];
      acc[0][nf] = __builtin_amdgcn_mfma_f32_16x16x32_bf16(a0, bw, acc[0][nf], 0, 0, 0);
      acc[1][nf] = __builtin_amdgcn_mfma_f32_16x16x32_bf16(a1, bw, acc[1][nf], 0, 0, 0);
      acc[2][nf] = __builtin_amdgcn_mfma_f32_16x16x32_bf16(a2, bw, acc[2][nf], 0, 0, 0);
      acc[3][nf] = __builtin_amdgcn_mfma_f32_16x16x32_bf16(a3, bw, acc[3][nf], 0, 0, 0);
    }
  }
  __syncthreads();

  unsigned short* stg = tl;                    // [64][136] bf16
  const int isgate = (ct >= 3);
#pragma unroll
  for (int nf = 0; nf < 2; nf++){
    const int c = C0 + nf*16 + l15;
    const float bv = isgate ? bz[c - 384] : bx[c];
#pragma unroll
    for (int m = 0; m < 4; m++){
#pragma unroll
      for (int r = 0; r < 4; r++){
        float val = acc[m][nf][r] + bv;
        if (isgate){ const float si = val * sigf_fast(val); val = sigf_fast(si); }
        stg[(m*16 + q*4 + r)*136 + (w*32 + nf*16 + l15)] = f2bf(val);
      }
    }
  }
  __syncthreads();

  {
    unsigned short* outp = isgate ? gate_bf : x_bf;
    const int cb = isgate ? (ct*128 - 384) : (ct*128);
#pragma unroll
    for (int i = 0; i < 4; i++){
      const int item = i*256 + t;
      const int row = item / 16, c8 = item % 16;
      *(short8*)&outp[(long)(row0 + row)*384 + cb + c8*8] =
          *(const short8*)&stg[row*136 + c8*8];
    }
  }
}

// ------ Stage B: depthwise conv + E->[B|C|D|u] proj (MFMA) + ZOH, both dirs ------
__global__ __launch_bounds__(256) void proj_mfma(
    const unsigned short* __restrict__ x_bf,
    const float* __restrict__ cwf, const float* __restrict__ cbf,
    const float* __restrict__ cwb, const float* __restrict__ cbb,
    const unsigned short* __restrict__ W4f, const unsigned short* __restrict__ W4b,
    const float* __restrict__ b4f, const float* __restrict__ b4b,
    const float* __restrict__ A_log,
    float* __restrict__ Af, float* __restrict__ Buf, float* __restrict__ Ctf,
    float* __restrict__ Ab, float* __restrict__ Bub, float* __restrict__ Ctb)
{
  __shared__ unsigned short xc[32 * 392];
  float* pj = (float*)xc;
  const int t = threadIdx.x;
  const int bid = blockIdx.x;
  const int dir = bid >> 10;
  const int r10 = bid & 1023;
  const int av = r10 >> 4, xv = r10 & 7, hv = (r10 >> 3) & 1;
  const int v = av*8 + xv;
  const int u = v*2 + hv;
  const int b = u >> 5;
  const int jt = dir ? (31 - (u & 31)) : (u & 31);
  const int j0 = jt * 32;
  const float* cw = dir ? cwb : cwf;
  const float* cb = dir ? cbb : cbf;
  const unsigned short* W4 = dir ? W4b : W4f;
  const float* b4 = dir ? b4b : b4f;
  float* Aout = dir ? Ab  : Af;
  float* Bout = dir ? Bub : Buf;
  float* Cout = dir ? Ctb : Ctf;

  {
    const long xrow = (long)b * 1024 * 384;
#pragma unroll
    for (int i = 0; i < 6; i++){
      const int idx = i*256 + t;
      const int r = idx / 48;
      const int e0 = (idx - r*48) * 8;
      const int jp = j0 + r;
      short8 xm = (short8){0,0,0,0,0,0,0,0};
      short8 xp = (short8){0,0,0,0,0,0,0,0};
      if (jp >= 1){
        const int js = dir ? 1024 - jp : jp - 1;
        xm = *(const short8*)&x_bf[xrow + (long)js*384 + e0];
      }
      short8 x0;
      {
        const int js = dir ? 1023 - jp : jp;
        x0 = *(const short8*)&x_bf[xrow + (long)js*384 + e0];
      }
      if (jp <= 1022){
        const int js = dir ? 1022 - jp : jp + 1;
        xp = *(const short8*)&x_bf[xrow + (long)js*384 + e0];
      }
      float wv[24], cbv[8];
#pragma unroll
      for (int vv = 0; vv < 6; vv++)
        *(float4*)&wv[vv*4] = *(const float4*)&cw[e0*3 + vv*4];
#pragma unroll
      for (int vv = 0; vv < 2; vv++)
        *(float4*)&cbv[vv*4] = *(const float4*)&cb[e0 + vv*4];
      short8 o;
#pragma unroll
      for (int m = 0; m < 8; m++){
        const float acc = fmaf(wv[3*m],   bf2f((unsigned short)xm[m]),
                          fmaf(wv[3*m+1], bf2f((unsigned short)x0[m]),
                          fmaf(wv[3*m+2], bf2f((unsigned short)xp[m]), cbv[m])));
        o[m] = (short)f2bf(acc);
      }
      *(short8*)&xc[r*392 + e0] = o;
    }
  }
  __syncthreads();

  const int lane = t & 63, w = t >> 6;
  const int l15 = lane & 15, q = lane >> 4;
  const int rt = w & 1, ng = w >> 1;
  f32x4 acc[2];
#pragma unroll
  for (int nf = 0; nf < 2; nf++) acc[nf] = (f32x4){0.f,0.f,0.f,0.f};
  const unsigned short* wb = W4 + (long)(ng*32 + l15)*384 + q*8;
#pragma unroll
  for (int ks = 0; ks < 12; ks++){
    const int k0 = ks * 32;
    short8 a = *(const short8*)&xc[(rt*16 + l15)*392 + k0 + q*8];
#pragma unroll
    for (int nf = 0; nf < 2; nf++){
      short8 bw = *(const short8*)&wb[nf*16*384 + k0];
      acc[nf] = __builtin_amdgcn_mfma_f32_16x16x32_bf16(a, bw, acc[nf], 0, 0, 0);
    }
  }
  __syncthreads();

  {
#pragma unroll
    for (int nf = 0; nf < 2; nf++){
      const int col = ng*32 + nf*16 + l15;
#pragma unroll
      for (int r = 0; r < 4; r++)
        pj[col*34 + rt*16 + q*4 + r] = acc[nf][r];
    }
  }
  __syncthreads();

  {
#pragma unroll
    for (int i = 0; i < 2; i++){
      const int idx = i*256 + t;
      const int n = idx >> 5, j = idx & 31;
      const float Bt  = pj[(     n)*34 + j] + b4[n];
      const float Ctv = pj[(16 + n)*34 + j] + b4[16 + n];
      const float dt  = softplus_fast(pj[(32 + n)*34 + j] + b4[32 + n]);
      const float u2  = pj[(48 + n)*34 + j] + b4[48 + n];
      const float Av  = -softplusf(A_log[n]);
      const float ab  = __expf(dt * Av);
      const float bu  = (ab - 1.f) * __builtin_amdgcn_rcpf(Av + 1e-6f) * Bt * u2;
      const int jp = j0 + j;
      const long base = ((long)b*16 + n) * 1024;
      Aout[base + jp] = ab;
      Bout[base + jp] = bu;
      Cout[base + (dir ? 1023 - jp : jp)] = Ctv;
    }
  }
}

// ---------------- Stage C: scan, both directions in one launch ----------------
__global__ __launch_bounds__(256) void scan2_kernel(
    const float* __restrict__ Af, const float* __restrict__ Buf, float* __restrict__ hsf,
    const float* __restrict__ Ab, const float* __restrict__ Bub, float* __restrict__ hsb)
{
  __shared__ float sA[256], sB[256];
  const int sel = blockIdx.x >> 9;
  const long base = (long)(blockIdx.x & 511) * 1024;
  const float* Abar = sel ? Ab  : Af;
  const float* Bu   = sel ? Bub : Buf;
  float* hs         = sel ? hsb : hsf;
  const int t = threadIdx.x;
  const float4 a4 = *reinterpret_cast<const float4*>(&Abar[base + t*4]);
  const float4 b4 = *reinterpret_cast<const float4*>(&Bu[base + t*4]);
  float A = a4.x, Bc = b4.x;
  Bc = fmaf(a4.y, Bc, b4.y); A *= a4.y;
  Bc = fmaf(a4.z, Bc, b4.z); A *= a4.z;
  Bc = fmaf(a4.w, Bc, b4.w); A *= a4.w;
  sA[t] = A; sB[t] = Bc;
  __syncthreads();
  for (int off = 1; off < 256; off <<= 1){
    const float cA = sA[t], cB = sB[t];
    float pA = 1.f, pB = 0.f;
    if (t >= off){ pA = sA[t - off]; pB = sB[t - off]; }
    __syncthreads();
    sA[t] = pA * cA;
    sB[t] = fmaf(cA, pB, cB);
    __syncthreads();
  }
  float h = (t > 0) ? sB[t - 1] : 0.f;
  float4 o;
  h = fmaf(a4.x, h, b4.x); o.x = h;
  h = fmaf(a4.y, h, b4.y); o.y = h;
  h = fmaf(a4.z, h, b4.z); o.z = h;
  h = fmaf(a4.w, h, b4.w); o.w = h;
  *reinterpret_cast<float4*>(&hs[base + t*4]) = o;
}

// ------- Stage D1: yr_gemm — s2 build + GEMM1(K=32) + gate -> yg_bf -------
// grid 1024 (32 rows), block 256 (4 waves: 2 row-tiles x 2 nf-halves).
// LDS: s2 2.5KB + stage 25.1KB = 27.6KB -> 5 blocks/CU.
__global__ __launch_bounds__(256) void yr_gemm(
    const float* __restrict__ hsf, const float* __restrict__ Ctf,
    const float* __restrict__ hsb, const float* __restrict__ Ctb,
    const unsigned short* __restrict__ gate_bf,
    const unsigned short* __restrict__ Wrt2, const float* __restrict__ br,
    unsigned short* __restrict__ yg_g)
{
  __shared__ unsigned short s2[32 * 40];       // 2,560 B (stride 80B: aligned b128)
  __shared__ unsigned short yg[32 * 392];      // 25,088 B
  const int t = threadIdx.x;
  const int bid = blockIdx.x;
  const int av = bid >> 4, xv = bid & 7, hv = (bid >> 3) & 1;
  const int v = av*8 + xv;                     // 64-row tile; XCD = v%8 = bid%8
  const int u = v*2 + hv;
  const int b  = u >> 5;
  const int j0 = (u & 31) * 32;

  { // s2[j][kk]: 4 items/thread
#pragma unroll
    for (int i = 0; i < 4; i++){
      const int idx = i*256 + t;
      const int j = idx & 31, kk = idx >> 5;
      float val;
      if (kk < 16){
        const long p = ((long)b*16 + kk)*1024 + j0 + j;
        val = hsf[p] * Ctf[p];
      } else {
        const long basen = ((long)b*16 + (kk - 16)) * 1024;
        val = hsb[basen + 1023 - (j0 + j)] * Ctb[basen + j0 + j];
      }
      s2[j*40 + kk] = f2bf(val);
    }
  }
  __syncthreads();

  const int lane = t & 63, w = t >> 6;
  const int l15 = lane & 15, q = lane >> 4;
  const int rt = w & 1, ng = w >> 1;

  { // GEMM1: one K=32 step, 12 nf per wave; y+2br staged bf16
    short8 a1 = *(const short8*)&s2[(rt*16 + l15)*40 + q*8];
    const unsigned short* wbp = Wrt2 + (long)l15*32 + q*8;
#pragma unroll
    for (int i = 0; i < 12; i++){
      const int nf = ng*12 + i;
      short8 bw = *(const short8*)&wbp[nf*16*32];
      f32x4 acc = (f32x4){0.f,0.f,0.f,0.f};
      acc = __builtin_amdgcn_mfma_f32_16x16x32_bf16(a1, bw, acc, 0, 0, 0);
      const int c = nf*16 + l15;
      const float brv = 2.f * br[c];
#pragma unroll
      for (int r = 0; r < 4; r++)
        yg[(rt*16 + q*4 + r)*392 + c] = f2bf(acc[r] + brv);
    }
  }
  __syncthreads();

  { // gate + coalesced store: 6 items/thread (32 rows x 48 short8)
#pragma unroll
    for (int i = 0; i < 6; i++){
      const int item = i*256 + t;
      const int row = item / 48;
      const int cb  = (item % 48) * 8;
      short8 y8 = *(const short8*)&yg[row*392 + cb];
      short8 g8 = *(const short8*)&gate_bf[((long)b*1024 + j0 + row)*384 + cb];
      short8 o;
#pragma unroll
      for (int m = 0; m < 8; m++)
        o[m] = (short)f2bf(bf2f((unsigned short)y8[m]) * bf2f((unsigned short)g8[m]));
      *(short8*)&yg_g[((long)b*1024 + j0 + row)*384 + cb] = o;
    }
  }
}

// ------- Stage D2: out_gemm — yg_bf @ Wot + tokens + bo -> out -------
// grid 1024 (32 rows), block 256 (4 waves: 2 row-tiles x 2 col-halves).
// LDS: union(in-tile 26.1KB bf16, stage 25.6KB f32) = 26.1KB -> 6 blocks/CU.
__global__ __launch_bounds__(256) void out_gemm(
    const unsigned short* __restrict__ yg_g,
    const unsigned short* __restrict__ Wot, const float* __restrict__ bo,
    const float* __restrict__ tokens, float* __restrict__ out)
{
  __shared__ float stgf[32 * 204];             // 26,112 B
  unsigned short* yt = (unsigned short*)stgf;  // in-tile [32][408] bf16
  const int t = threadIdx.x;
  const int bid = blockIdx.x;
  const int av = bid >> 4, xv = bid & 7, hv = (bid >> 3) & 1;
  const int v = av*8 + xv;                     // XCD = v%8 = bid%8
  const int u = v*2 + hv;
  const int b  = u >> 5;
  const int j0 = (u & 31) * 32;

  { // load yg tile: 32 rows x 48 short8 = 1536 items, 6/thread
#pragma unroll
    for (int i = 0; i < 6; i++){
      const int item = i*256 + t;
      const int row = item / 48, c8 = item % 48;
      *(short8*)&yt[row*408 + c8*8] =
          *(const short8*)&yg_g[((long)b*1024 + j0 + row)*384 + c8*8];
    }
  }
  __syncthreads();

  const int lane = t & 63, w = t >> 6;
  const int l15 = lane & 15, q = lane >> 4;
  const int rt = w & 1, cg = w >> 1;           // 16 rows x 96 cols per wave

  f32x4 acc[6];
#pragma unroll
  for (int i = 0; i < 6; i++) acc[i] = (f32x4){0.f,0.f,0.f,0.f};
  {
    const unsigned short* wbp = Wot + (long)(cg*96 + l15)*384 + q*8;
#pragma unroll
    for (int ks = 0; ks < 12; ks++){
      const int k0 = ks * 32;
      short8 a = *(const short8*)&yt[(rt*16 + l15)*408 + k0 + q*8];
#pragma unroll
      for (int i = 0; i < 6; i++){
        short8 bw = *(const short8*)&wbp[(long)i*16*384 + k0];
        acc[i] = __builtin_amdgcn_mfma_f32_16x16x32_bf16(a, bw, acc[i], 0, 0, 0);
      }
    }
  }
  __syncthreads();   // all yt reads done; reuse as f32 staging

  { // stage f32 with Gray-code block rotation
    const int gq = q ^ (q >> 1);
#pragma unroll
    for (int i = 0; i < 6; i++){
      const int nf = cg*6 + i;
      const int c = nf*16 + l15;
      const float bv = bo[c];
      const int scol = ((nf + gq) % 12)*16 + l15;
#pragma unroll
      for (int r = 0; r < 4; r++)
        stgf[(rt*16 + q*4 + r)*204 + scol] = acc[i][r] + bv;
    }
  }
  __syncthreads();

  { // cooperative: tokens float4 + staged + store float4. 6 items/thread
#pragma unroll
    for (int i = 0; i < 6; i++){
      const int item = i*256 + t;            // 32 rows x 48 float4
      const int row = item / 48;
      const int c4  = (item % 48) * 4;
      const int qq = (row >> 2) & 3;
      const int gg = qq ^ (qq >> 1);
      const int nf = c4 / 16;
      const int scol = ((nf + gg) % 12)*16 + (c4 % 16);
      float4 vv = *(const float4*)&stgf[row*204 + scol];
      const long R = (long)b*1024 + j0 + row;
      const float4 tk = *(const float4*)&tokens[R*192 + c4];
      vv.x += tk.x; vv.y += tk.y; vv.z += tk.z; vv.w += tk.w;
      *(float4*)&out[R*192 + c4] = vv;
    }
  }
}

extern "C" void kernel_launch(void* const* d_in, const int* in_sizes, int n_in,
                              void* d_out, int out_size, void* d_ws, size_t ws_size,
                              hipStream_t stream)
{
  const float* tokens  = (const float*)d_in[0];
  const float* norm_g  = (const float*)d_in[1];
  const float* norm_b  = (const float*)d_in[2];
  const float* Wx      = (const float*)d_in[3];
  const float* bx      = (const float*)d_in[4];
  const float* Wz      = (const float*)d_in[5];
  const float* bz      = (const float*)d_in[6];
  const float* convf_w = (const float*)d_in[7];
  const float* convf_b = (const float*)d_in[8];
  const float* convb_w = (const float*)d_in[9];
  const float* convb_b = (const float*)d_in[10];
  const float* WBf     = (const float*)d_in[11];
  const float* bBf     = (const float*)d_in[12];
  const float* WCf     = (const float*)d_in[13];
  const float* bCf     = (const float*)d_in[14];
  const float* WDf     = (const float*)d_in[15];
  const float* bDf     = (const float*)d_in[16];
  const float* WBb     = (const float*)d_in[17];
  const float* bBb     = (const float*)d_in[18];
  const float* WCb     = (const float*)d_in[19];
  const float* bCb     = (const float*)d_in[20];
  const float* WDb     = (const float*)d_in[21];
  const float* bDb     = (const float*)d_in[22];
  const float* A_log   = (const float*)d_in[23];
  const float* Wi      = (const float*)d_in[24];
  const float* bi      = (const float*)d_in[25];
  const float* Wr      = (const float*)d_in[26];
  const float* br      = (const float*)d_in[27];
  const float* Wo      = (const float*)d_in[28];
  const float* bo      = (const float*)d_in[29];

  char* ws = (char*)d_ws;
  unsigned short* x_bf    = (unsigned short*)(ws + 0);          // 25,165,824 B (reused as yg_g)
  unsigned short* gate_bf = (unsigned short*)(ws + 25165824);   // 25,165,824 B
  unsigned short* Wxz_t   = (unsigned short*)(ws + 50331648);   //    294,912 B
  unsigned short* W4f_t   = (unsigned short*)(ws + 50626560);   //     49,152 B
  unsigned short* W4b_t   = (unsigned short*)(ws + 50675712);   //     49,152 B
  unsigned short* Wrt2    = (unsigned short*)(ws + 50724864);   //     24,576 B
  unsigned short* Wot     = (unsigned short*)(ws + 50749440);   //    147,456 B
  float* b4f = (float*)(ws + 50896896);                         //        256 B
  float* b4b = (float*)(ws + 50897152);                         //        256 B
  float* Af  = (float*)(ws + 50897408);
  float* Buf = (float*)(ws + 52994560);
  float* Ctf = (float*)(ws + 55091712);
  float* hsf = (float*)(ws + 57188864);
  float* Ab  = (float*)(ws + 59286016);
  float* Bub = (float*)(ws + 61383168);
  float* Ctb = (float*)(ws + 63480320);
  float* hsb = (float*)(ws + 65577472);
  unsigned short* t_bf = (unsigned short*)(ws + 67674624);      // 12,582,912 B -> ~80.3 MB
  unsigned short* yg_g = x_bf;                                  // x_bf dead after proj

  prep_kernel<<<1105, 256, 0, stream>>>(Wx, Wz, WBf, WCf, WDf, WBb, WCb, WDb,
                                        Wi, Wr, Wo, bBf, bCf, bDf, bBb, bCb, bDb, bi,
                                        Wxz_t, W4f_t, W4b_t, Wrt2, Wot, b4f, b4b);
  ln_kernel<<<1024, 256, 0, stream>>>(tokens, norm_g, norm_b, t_bf);
  xz_gemm<<<3072, 256, 0, stream>>>(t_bf, Wxz_t, bx, bz, x_bf, gate_bf);
  proj_mfma<<<2048, 256, 0, stream>>>(x_bf, convf_w, convf_b, convb_w, convb_b,
                                      W4f_t, W4b_t, b4f, b4b, A_log,
                                      Af, Buf, Ctf, Ab, Bub, Ctb);
  scan2_kernel<<<1024, 256, 0, stream>>>(Af, Buf, hsf, Ab, Bub, hsb);
  yr_gemm<<<1024, 256, 0, stream>>>(hsf, Ctf, hsb, Ctb, gate_bf, Wrt2, br, yg_g);
  out_gemm<<<1024, 256, 0, stream>>>(yg_g, Wot, bo, tokens, (float*)d_out);
}

// Round 20
// 132.268 us; speedup vs baseline: 1.0756x; 1.0756x over previous
//
#include <hip/hip_runtime.h>
#include <math.h>

// VimBlock: B=32, J=1024, D=192, E=384, N=16, K=3.
// MFMA bf16; XCD-affinity swizzle everywhere (rb=(row/64)%8 -> bid%8).
// R20: proj merges BOTH scan directions per x-tile (halves x_bf reads);
// Stage D reverted to R18's fused final_mfma.

typedef __attribute__((ext_vector_type(8))) short short8;
typedef __attribute__((ext_vector_type(4))) float f32x4;

__device__ __forceinline__ unsigned short f2bf(float f){
  union { float f; unsigned u; } v; v.f = f;
  unsigned r = v.u + 0x7FFFu + ((v.u >> 16) & 1u);   // RNE
  return (unsigned short)(r >> 16);
}
__device__ __forceinline__ float bf2f(unsigned short s){
  union { unsigned u; float f; } v; v.u = ((unsigned)s) << 16;
  return v.f;
}
__device__ __forceinline__ float softplusf(float x){
  return (x > 20.f) ? x : log1pf(expf(x));
}
__device__ __forceinline__ float softplus_fast(float x){
  return (x > 20.f) ? x : __logf(1.f + __expf(x));
}
__device__ __forceinline__ float sigf_fast(float x){
  return __builtin_amdgcn_rcpf(1.f + __expf(-x));
}

// ---------------- prep: pack weights to bf16 transposed layouts ----------------
__global__ __launch_bounds__(256) void prep_kernel(
    const float* __restrict__ Wx, const float* __restrict__ Wz,
    const float* __restrict__ WBf, const float* __restrict__ WCf,
    const float* __restrict__ WDf, const float* __restrict__ WBb,
    const float* __restrict__ WCb, const float* __restrict__ WDb,
    const float* __restrict__ Wi, const float* __restrict__ Wr,
    const float* __restrict__ Wo,
    const float* __restrict__ bBf, const float* __restrict__ bCf,
    const float* __restrict__ bDf, const float* __restrict__ bBb,
    const float* __restrict__ bCb, const float* __restrict__ bDb,
    const float* __restrict__ bi,
    unsigned short* __restrict__ Wxz_t, unsigned short* __restrict__ W4f_t,
    unsigned short* __restrict__ W4b_t, unsigned short* __restrict__ Wrt2,
    unsigned short* __restrict__ Wot, float* __restrict__ b4f,
    float* __restrict__ b4b)
{
  int idx = blockIdx.x * 256 + threadIdx.x;
  if (idx < 147456){ int n = idx / 192, k = idx % 192;
    Wxz_t[idx] = f2bf(n < 384 ? Wx[k*384 + n] : Wz[k*384 + n - 384]); return; }
  idx -= 147456;
  if (idx < 24576){ int n = idx / 384, k = idx % 384;
    const float* W = (n<16)?WBf:(n<32)?WCf:(n<48)?WDf:Wi;
    W4f_t[idx] = f2bf(W[k*16 + (n&15)]); return; }
  idx -= 24576;
  if (idx < 24576){ int n = idx / 384, k = idx % 384;
    const float* W = (n<16)?WBb:(n<32)?WCb:(n<48)?WDb:Wi;
    W4b_t[idx] = f2bf(W[k*16 + (n&15)]); return; }
  idx -= 24576;
  if (idx < 12288){ int n = idx / 32, k = idx % 32;
    Wrt2[idx] = f2bf(Wr[(k&15)*384 + n]); return; }
  idx -= 12288;
  if (idx < 73728){ int n = idx / 384, k = idx % 384;
    Wot[idx] = f2bf(Wo[k*192 + n]); return; }
  idx -= 73728;
  if (idx < 64){
    const float* bsel = (idx<16)?bBf:(idx<32)?bCf:(idx<48)?bDf:bi;
    b4f[idx] = bsel[idx & 15]; return; }
  idx -= 64;
  if (idx < 64){
    const float* bsel = (idx<16)?bBb:(idx<32)?bCb:(idx<48)?bDb:bi;
    b4b[idx] = bsel[idx & 15]; return; }
}

// ---------------- Stage A1: LayerNorm -> t_bf ----------------
__global__ __launch_bounds__(256) void ln_kernel(
    const float* __restrict__ tokens, const float* __restrict__ g,
    const float* __restrict__ nb, unsigned short* __restrict__ t_bf)
{
  __shared__ unsigned short s[32 * 200];
  const int t = threadIdx.x;
  const int bid = blockIdx.x;
  const int a = bid >> 4, x = bid & 7, h = (bid >> 3) & 1;
  const int v = a*8 + x;
  const int row0 = (v*2 + h) * 32;
  {
    const int r = t >> 3, l8 = t & 7;
    const float* tr = tokens + (long)(row0 + r) * 192;
    float vv[24], sm = 0.f, sq = 0.f;
#pragma unroll
    for (int i = 0; i < 24; i++){ float xx = tr[l8 + 8*i]; vv[i] = xx; sm += xx; sq += xx*xx; }
#pragma unroll
    for (int m = 1; m < 8; m <<= 1){ sm += __shfl_xor(sm, m); sq += __shfl_xor(sq, m); }
    const float mu = sm * (1.f/192.f);
    const float rstd = rsqrtf(sq * (1.f/192.f) - mu*mu + 1e-5f);
#pragma unroll
    for (int i = 0; i < 24; i++){
      const int d = l8 + 8*i;
      s[r*200 + d] = f2bf((vv[i] - mu)*rstd*g[d] + nb[d]);
    }
  }
  __syncthreads();
  {
#pragma unroll
    for (int i = 0; i < 3; i++){
      const int item = i*256 + t;
      const int row = item / 24, c8 = item % 24;
      *(short8*)&t_bf[(long)(row0 + row)*192 + c8*8] =
          *(const short8*)&s[row*200 + c8*8];
    }
  }
}

// ---------------- Stage A2: streaming GEMM t_bf @ Wxz -> x_bf / gate_bf ----------------
__global__ __launch_bounds__(256) void xz_gemm(
    const unsigned short* __restrict__ t_bf,
    const unsigned short* __restrict__ Wxz_t,
    const float* __restrict__ bx, const float* __restrict__ bz,
    unsigned short* __restrict__ x_bf, unsigned short* __restrict__ gate_bf)
{
  __shared__ unsigned short tl[64 * 200];
  const int t = threadIdx.x;
  const int bid = blockIdx.x;
  const int a = bid / 48, rem = bid % 48;
  const int ct = rem >> 3;
  const int rt = a*8 + (rem & 7);
  const int row0 = rt * 64;

  {
#pragma unroll
    for (int i = 0; i < 6; i++){
      const int item = i*256 + t;
      const int row = item / 24, c8 = item % 24;
      *(short8*)&tl[row*200 + c8*8] =
          *(const short8*)&t_bf[(long)(row0 + row)*192 + c8*8];
    }
  }
  __syncthreads();

  const int lane = t & 63, w = t >> 6;
  const int l15 = lane & 15, q = lane >> 4;
  const int C0 = ct*128 + w*32;

  f32x4 acc[4][2];
#pragma unroll
  for (int m = 0; m < 4; m++)
#pragma unroll
    for (int nf = 0; nf < 2; nf++) acc[m][nf] = (f32x4){0.f,0.f,0.f,0.f};

  const unsigned short* wb = Wxz_t + (long)(C0 + l15)*192 + q*8;
#pragma unroll
  for (int ks = 0; ks < 6; ks++){
    const int k0 = ks * 32;
    short8 a0 = *(const short8*)&tl[(     l15)*200 + k0 + q*8];
    short8 a1 = *(const short8*)&tl[(16 + l15)*200 + k0 + q*8];
    short8 a2 = *(const short8*)&tl[(32 + l15)*200 + k0 + q*8];
    short8 a3 = *(const short8*)&tl[(48 + l15)*200 + k0 + q*8];
#pragma unroll
    for (int nf = 0; nf < 2; nf++){
      short8 bw = *(const short8*)&wb[nf*16*192 + k0];
      acc[0][nf] = __builtin_amdgcn_mfma_f32_16x16x32_bf16(a0, bw, acc[0][nf], 0, 0, 0);
      acc[1][nf] = __builtin_amdgcn_mfma_f32_16x16x32_bf16(a1, bw, acc[1][nf], 0, 0, 0);
      acc[2][nf] = __builtin_amdgcn_mfma_f32_16x16x32_bf16(a2, bw, acc[2][nf], 0, 0, 0);
      acc[3][nf] = __builtin_amdgcn_mfma_f32_16x16x32_bf16(a3, bw, acc[3][nf], 0, 0, 0);
    }
  }
  __syncthreads();

  unsigned short* stg = tl;                    // [64][136] bf16
  const int isgate = (ct >= 3);
#pragma unroll
  for (int nf = 0; nf < 2; nf++){
    const int c = C0 + nf*16 + l15;
    const float bv = isgate ? bz[c - 384] : bx[c];
#pragma unroll
    for (int m = 0; m < 4; m++){
#pragma unroll
      for (int r = 0; r < 4; r++){
        float val = acc[m][nf][r] + bv;
        if (isgate){ const float si = val * sigf_fast(val); val = sigf_fast(si); }
        stg[(m*16 + q*4 + r)*136 + (w*32 + nf*16 + l15)] = f2bf(val);
      }
    }
  }
  __syncthreads();

  {
    unsigned short* outp = isgate ? gate_bf : x_bf;
    const int cb = isgate ? (ct*128 - 384) : (ct*128);
#pragma unroll
    for (int i = 0; i < 4; i++){
      const int item = i*256 + t;
      const int row = item / 16, c8 = item % 16;
      *(short8*)&outp[(long)(row0 + row)*384 + cb + c8*8] =
          *(const short8*)&stg[row*136 + c8*8];
    }
  }
}

// ------ Stage B: merged-direction conv + proj + ZOH ------
// grid 1024 (32 forward rows/block; backward scan block [992-j0, 1023-j0]
// reads the SAME x rows). block 256 (4 waves: 2 row-tiles x 2 nf-pairs, both dirs).
// LDS: xcf+xcb = 50,176 B; pjf/pjb aliased after MFMA.
__global__ __launch_bounds__(256) void proj_mfma(
    const unsigned short* __restrict__ x_bf,
    const float* __restrict__ cwf, const float* __restrict__ cbf,
    const float* __restrict__ cwb, const float* __restrict__ cbb,
    const unsigned short* __restrict__ W4f, const unsigned short* __restrict__ W4b,
    const float* __restrict__ b4f, const float* __restrict__ b4b,
    const float* __restrict__ A_log,
    float* __restrict__ Af, float* __restrict__ Buf, float* __restrict__ Ctf,
    float* __restrict__ Ab, float* __restrict__ Bub, float* __restrict__ Ctb)
{
  __shared__ unsigned short xcf[32 * 392];     // 25,088 B; pjf aliased after MFMA
  __shared__ unsigned short xcb[32 * 392];     // 25,088 B; pjb aliased after MFMA
  float* pjf = (float*)xcf;                    // [64][34] f32 = 8,704 B
  float* pjb = (float*)xcb;
  const int t = threadIdx.x;
  const int bid = blockIdx.x;
  const int av = bid >> 4, xv = bid & 7, hv = (bid >> 3) & 1;
  const int v = av*8 + xv;                     // 64-row tile; XCD = v%8 = bid%8
  const int u = v*2 + hv;
  const int b  = u >> 5;
  const int j0 = (u & 31) * 32;                // forward rows [j0, j0+32)
  const int jb0 = 992 - j0;                    // backward scan block [jb0, jb0+32)

  { // conv both directions from ONE x-load: 6 items x (row, 8-wide e-slice)
    const long xrow = (long)b * 1024 * 384;
#pragma unroll
    for (int i = 0; i < 6; i++){
      const int idx = i*256 + t;
      const int r = idx / 48;
      const int e0 = (idx - r*48) * 8;
      const int jp = j0 + r;
      short8 xm = (short8){0,0,0,0,0,0,0,0};
      short8 xp = (short8){0,0,0,0,0,0,0,0};
      if (jp >= 1)    xm = *(const short8*)&x_bf[xrow + (long)(jp-1)*384 + e0];
      short8 x0      = *(const short8*)&x_bf[xrow + (long)jp*384 + e0];
      if (jp <= 1022) xp = *(const short8*)&x_bf[xrow + (long)(jp+1)*384 + e0];

      float xmf[8], x0f[8], xpf[8];
#pragma unroll
      for (int m = 0; m < 8; m++){
        xmf[m] = bf2f((unsigned short)xm[m]);
        x0f[m] = bf2f((unsigned short)x0[m]);
        xpf[m] = bf2f((unsigned short)xp[m]);
      }
      { // forward: of = wf0*xm + wf1*x0 + wf2*xp + cbf
        float wv[24], cbv[8];
#pragma unroll
        for (int vv = 0; vv < 6; vv++)
          *(float4*)&wv[vv*4] = *(const float4*)&cwf[e0*3 + vv*4];
#pragma unroll
        for (int vv = 0; vv < 2; vv++)
          *(float4*)&cbv[vv*4] = *(const float4*)&cbf[e0 + vv*4];
        short8 o;
#pragma unroll
        for (int m = 0; m < 8; m++)
          o[m] = (short)f2bf(fmaf(wv[3*m], xmf[m],
                            fmaf(wv[3*m+1], x0f[m],
                            fmaf(wv[3*m+2], xpf[m], cbv[m]))));
        *(short8*)&xcf[r*392 + e0] = o;
      }
      { // backward at scan pos s=1023-jp (tile row 31-r): ob = wb0*xp + wb1*x0 + wb2*xm + cbb
        float wv[24], cbv[8];
#pragma unroll
        for (int vv = 0; vv < 6; vv++)
          *(float4*)&wv[vv*4] = *(const float4*)&cwb[e0*3 + vv*4];
#pragma unroll
        for (int vv = 0; vv < 2; vv++)
          *(float4*)&cbv[vv*4] = *(const float4*)&cbb[e0 + vv*4];
        short8 o;
#pragma unroll
        for (int m = 0; m < 8; m++)
          o[m] = (short)f2bf(fmaf(wv[3*m], xpf[m],
                            fmaf(wv[3*m+1], x0f[m],
                            fmaf(wv[3*m+2], xmf[m], cbv[m]))));
        *(short8*)&xcb[(31 - r)*392 + e0] = o;
      }
    }
  }
  __syncthreads();

  // MFMA: wave w -> row-tile rt = w&1 (16 rows), nf-pair ng = w>>1; BOTH dirs
  const int lane = t & 63, w = t >> 6;
  const int l15 = lane & 15, q = lane >> 4;
  const int rt = w & 1, ng = w >> 1;
  f32x4 accF[2], accB[2];
#pragma unroll
  for (int nf = 0; nf < 2; nf++){ accF[nf] = (f32x4){0.f,0.f,0.f,0.f};
                                  accB[nf] = (f32x4){0.f,0.f,0.f,0.f}; }
  const unsigned short* wbF = W4f + (long)(ng*32 + l15)*384 + q*8;
  const unsigned short* wbB = W4b + (long)(ng*32 + l15)*384 + q*8;
#pragma unroll
  for (int ks = 0; ks < 12; ks++){
    const int k0 = ks * 32;
    short8 aF = *(const short8*)&xcf[(rt*16 + l15)*392 + k0 + q*8];
    short8 aB = *(const short8*)&xcb[(rt*16 + l15)*392 + k0 + q*8];
#pragma unroll
    for (int nf = 0; nf < 2; nf++){
      short8 bwF = *(const short8*)&wbF[nf*16*384 + k0];
      short8 bwB = *(const short8*)&wbB[nf*16*384 + k0];
      accF[nf] = __builtin_amdgcn_mfma_f32_16x16x32_bf16(aF, bwF, accF[nf], 0, 0, 0);
      accB[nf] = __builtin_amdgcn_mfma_f32_16x16x32_bf16(aB, bwB, accB[nf], 0, 0, 0);
    }
  }
  __syncthreads();   // all MFMA reads done before pj overwrites

  { // stage raw projections: pj[col][row], both dirs
#pragma unroll
    for (int nf = 0; nf < 2; nf++){
      const int col = ng*32 + nf*16 + l15;
#pragma unroll
      for (int r = 0; r < 4; r++){
        pjf[col*34 + rt*16 + q*4 + r] = accF[nf][r];
        pjb[col*34 + rt*16 + q*4 + r] = accB[nf][r];
      }
    }
  }
  __syncthreads();

  { // ZOH + coalesced (B,N,J) writes: 2 items/thread per direction
#pragma unroll
    for (int i = 0; i < 2; i++){
      const int idx = i*256 + t;
      const int n = idx >> 5, j = idx & 31;
      const float Av  = -softplusf(A_log[n]);
      const float rAv = __builtin_amdgcn_rcpf(Av + 1e-6f);
      const long base = ((long)b*16 + n) * 1024;
      { // forward
        const float Bt  = pjf[(     n)*34 + j] + b4f[n];
        const float Ctv = pjf[(16 + n)*34 + j] + b4f[16 + n];
        const float dt  = softplus_fast(pjf[(32 + n)*34 + j] + b4f[32 + n]);
        const float u2  = pjf[(48 + n)*34 + j] + b4f[48 + n];
        const float ab  = __expf(dt * Av);
        Af [base + j0 + j] = ab;
        Buf[base + j0 + j] = (ab - 1.f) * rAv * Bt * u2;
        Ctf[base + j0 + j] = Ctv;
      }
      { // backward (scan pos s = jb0 + j; Ct at output pos 1023 - s)
        const float Bt  = pjb[(     n)*34 + j] + b4b[n];
        const float Ctv = pjb[(16 + n)*34 + j] + b4b[16 + n];
        const float dt  = softplus_fast(pjb[(32 + n)*34 + j] + b4b[32 + n]);
        const float u2  = pjb[(48 + n)*34 + j] + b4b[48 + n];
        const float ab  = __expf(dt * Av);
        Ab [base + jb0 + j] = ab;
        Bub[base + jb0 + j] = (ab - 1.f) * rAv * Bt * u2;
        Ctb[base + 1023 - (jb0 + j)] = Ctv;
      }
    }
  }
}

// ---------------- Stage C: scan, both directions in one launch ----------------
__global__ __launch_bounds__(256) void scan2_kernel(
    const float* __restrict__ Af, const float* __restrict__ Buf, float* __restrict__ hsf,
    const float* __restrict__ Ab, const float* __restrict__ Bub, float* __restrict__ hsb)
{
  __shared__ float sA[256], sB[256];
  const int sel = blockIdx.x >> 9;
  const long base = (long)(blockIdx.x & 511) * 1024;
  const float* Abar = sel ? Ab  : Af;
  const float* Bu   = sel ? Bub : Buf;
  float* hs         = sel ? hsb : hsf;
  const int t = threadIdx.x;
  const float4 a4 = *reinterpret_cast<const float4*>(&Abar[base + t*4]);
  const float4 b4 = *reinterpret_cast<const float4*>(&Bu[base + t*4]);
  float A = a4.x, Bc = b4.x;
  Bc = fmaf(a4.y, Bc, b4.y); A *= a4.y;
  Bc = fmaf(a4.z, Bc, b4.z); A *= a4.z;
  Bc = fmaf(a4.w, Bc, b4.w); A *= a4.w;
  sA[t] = A; sB[t] = Bc;
  __syncthreads();
  for (int off = 1; off < 256; off <<= 1){
    const float cA = sA[t], cB = sB[t];
    float pA = 1.f, pB = 0.f;
    if (t >= off){ pA = sA[t - off]; pB = sB[t - off]; }
    __syncthreads();
    sA[t] = pA * cA;
    sB[t] = fmaf(cA, pB, cB);
    __syncthreads();
  }
  float h = (t > 0) ? sB[t - 1] : 0.f;
  float4 o;
  h = fmaf(a4.x, h, b4.x); o.x = h;
  h = fmaf(a4.y, h, b4.y); o.y = h;
  h = fmaf(a4.z, h, b4.z); o.z = h;
  h = fmaf(a4.w, h, b4.w); o.w = h;
  *reinterpret_cast<float4*>(&hs[base + t*4]) = o;
}

// ------- Stage D (R18 fused): grid 2048 (16 rows), LDS ~14 KB -------
__global__ __launch_bounds__(256) void final_mfma(
    const float* __restrict__ tokens, const unsigned short* __restrict__ gate_bf,
    const float* __restrict__ hsf, const float* __restrict__ Ctf,
    const float* __restrict__ hsb, const float* __restrict__ Ctb,
    const unsigned short* __restrict__ Wrt2, const float* __restrict__ br,
    const unsigned short* __restrict__ Wot, const float* __restrict__ bo,
    float* __restrict__ out)
{
  __shared__ unsigned short s2[16 * 36];       // 1,152 B
  __shared__ float stgf[16 * 200];             // 12,800 B; aliased as yg[16][388] bf16
  unsigned short* yg = (unsigned short*)stgf;
  const int t = threadIdx.x;
  const int bid = blockIdx.x;
  const int a = bid >> 5, x = bid & 7, p = (bid >> 3) & 3;
  const int v = a*8 + x;                       // 64-row tile; XCD = v%8 = bid%8
  const int u16 = v*4 + p;                     // 16-row unit
  const int b  = u16 >> 6;
  const int j0 = (u16 & 63) * 16;

  {
#pragma unroll
    for (int i = 0; i < 2; i++){
      const int idx = i*256 + t;
      const int j = idx & 15, kk = idx >> 4;
      float val;
      if (kk < 16){
        const long pp = ((long)b*16 + kk)*1024 + j0 + j;
        val = hsf[pp] * Ctf[pp];
      } else {
        const long basen = ((long)b*16 + (kk - 16)) * 1024;
        val = hsb[basen + 1023 - (j0 + j)] * Ctb[basen + j0 + j];
      }
      s2[j*36 + kk] = f2bf(val);
    }
  }
  __syncthreads();

  const int lane = t & 63, w = t >> 6;
  const int l15 = lane & 15, q = lane >> 4;

  {
    short8 a1 = *(const short8*)&s2[l15*36 + q*8];
    const unsigned short* wbp = Wrt2 + (long)l15*32 + q*8;
#pragma unroll
    for (int i = 0; i < 6; i++){
      const int nf = w*6 + i;
      short8 bw = *(const short8*)&wbp[nf*16*32];
      f32x4 acc = (f32x4){0.f,0.f,0.f,0.f};
      acc = __builtin_amdgcn_mfma_f32_16x16x32_bf16(a1, bw, acc, 0, 0, 0);
      const int c = nf*16 + l15;
      const float brv = 2.f * br[c];
#pragma unroll
      for (int r = 0; r < 4; r++)
        yg[(q*4 + r)*388 + c] = f2bf(acc[r] + brv);
    }
  }
  __syncthreads();

  {
#pragma unroll
    for (int i = 0; i < 3; i++){
      const int item = i*256 + t;
      const int row = item / 48;
      const int cb  = (item % 48) * 8;
      short8 y8 = *(const short8*)&yg[row*388 + cb];
      short8 g8 = *(const short8*)&gate_bf[((long)b*1024 + j0 + row)*384 + cb];
      short8 o;
#pragma unroll
      for (int m = 0; m < 8; m++)
        o[m] = (short)f2bf(bf2f((unsigned short)y8[m]) * bf2f((unsigned short)g8[m]));
      *(short8*)&yg[row*388 + cb] = o;
    }
  }
  __syncthreads();

  f32x4 acc[3];
  {
#pragma unroll
    for (int i = 0; i < 3; i++) acc[i] = (f32x4){0.f,0.f,0.f,0.f};
    const unsigned short* wbp = Wot + (long)l15*384 + q*8;
#pragma unroll
    for (int ks = 0; ks < 12; ks++){
      const int k0 = ks * 32;
      short8 a2 = *(const short8*)&yg[l15*388 + k0 + q*8];
#pragma unroll
      for (int i = 0; i < 3; i++){
        const int nf = w*3 + i;
        short8 bw = *(const short8*)&wbp[(long)nf*16*384 + k0];
        acc[i] = __builtin_amdgcn_mfma_f32_16x16x32_bf16(a2, bw, acc[i], 0, 0, 0);
      }
    }
  }
  __syncthreads();

  {
    const int gq = q ^ (q >> 1);
#pragma unroll
    for (int i = 0; i < 3; i++){
      const int nf = w*3 + i;
      const int c = nf*16 + l15;
      const float bv = bo[c];
      const int scol = ((nf + gq) % 12)*16 + l15;
#pragma unroll
      for (int r = 0; r < 4; r++)
        stgf[(q*4 + r)*200 + scol] = acc[i][r] + bv;
    }
  }
  __syncthreads();

  {
#pragma unroll
    for (int i = 0; i < 3; i++){
      const int item = i*256 + t;
      const int row = item / 48;
      const int c4  = (item % 48) * 4;
      const int qq = (row >> 2) & 3;
      const int gg = qq ^ (qq >> 1);
      const int nf = c4 / 16;
      const int scol = ((nf + gg) % 12)*16 + (c4 % 16);
      float4 vv = *(const float4*)&stgf[row*200 + scol];
      const long R = (long)b*1024 + j0 + row;
      const float4 tk = *(const float4*)&tokens[R*192 + c4];
      vv.x += tk.x; vv.y += tk.y; vv.z += tk.z; vv.w += tk.w;
      *(float4*)&out[R*192 + c4] = vv;
    }
  }
}

extern "C" void kernel_launch(void* const* d_in, const int* in_sizes, int n_in,
                              void* d_out, int out_size, void* d_ws, size_t ws_size,
                              hipStream_t stream)
{
  const float* tokens  = (const float*)d_in[0];
  const float* norm_g  = (const float*)d_in[1];
  const float* norm_b  = (const float*)d_in[2];
  const float* Wx      = (const float*)d_in[3];
  const float* bx      = (const float*)d_in[4];
  const float* Wz      = (const float*)d_in[5];
  const float* bz      = (const float*)d_in[6];
  const float* convf_w = (const float*)d_in[7];
  const float* convf_b = (const float*)d_in[8];
  const float* convb_w = (const float*)d_in[9];
  const float* convb_b = (const float*)d_in[10];
  const float* WBf     = (const float*)d_in[11];
  const float* bBf     = (const float*)d_in[12];
  const float* WCf     = (const float*)d_in[13];
  const float* bCf     = (const float*)d_in[14];
  const float* WDf     = (const float*)d_in[15];
  const float* bDf     = (const float*)d_in[16];
  const float* WBb     = (const float*)d_in[17];
  const float* bBb     = (const float*)d_in[18];
  const float* WCb     = (const float*)d_in[19];
  const float* bCb     = (const float*)d_in[20];
  const float* WDb     = (const float*)d_in[21];
  const float* bDb     = (const float*)d_in[22];
  const float* A_log   = (const float*)d_in[23];
  const float* Wi      = (const float*)d_in[24];
  const float* bi      = (const float*)d_in[25];
  const float* Wr      = (const float*)d_in[26];
  const float* br      = (const float*)d_in[27];
  const float* Wo      = (const float*)d_in[28];
  const float* bo      = (const float*)d_in[29];

  char* ws = (char*)d_ws;
  unsigned short* x_bf    = (unsigned short*)(ws + 0);          // 25,165,824 B
  unsigned short* gate_bf = (unsigned short*)(ws + 25165824);   // 25,165,824 B
  unsigned short* Wxz_t   = (unsigned short*)(ws + 50331648);   //    294,912 B
  unsigned short* W4f_t   = (unsigned short*)(ws + 50626560);   //     49,152 B
  unsigned short* W4b_t   = (unsigned short*)(ws + 50675712);   //     49,152 B
  unsigned short* Wrt2    = (unsigned short*)(ws + 50724864);   //     24,576 B
  unsigned short* Wot     = (unsigned short*)(ws + 50749440);   //    147,456 B
  float* b4f = (float*)(ws + 50896896);                         //        256 B
  float* b4b = (float*)(ws + 50897152);                         //        256 B
  float* Af  = (float*)(ws + 50897408);
  float* Buf = (float*)(ws + 52994560);
  float* Ctf = (float*)(ws + 55091712);
  float* hsf = (float*)(ws + 57188864);
  float* Ab  = (float*)(ws + 59286016);
  float* Bub = (float*)(ws + 61383168);
  float* Ctb = (float*)(ws + 63480320);
  float* hsb = (float*)(ws + 65577472);
  unsigned short* t_bf = (unsigned short*)(ws + 67674624);      // 12,582,912 B -> ~80.3 MB

  prep_kernel<<<1105, 256, 0, stream>>>(Wx, Wz, WBf, WCf, WDf, WBb, WCb, WDb,
                                        Wi, Wr, Wo, bBf, bCf, bDf, bBb, bCb, bDb, bi,
                                        Wxz_t, W4f_t, W4b_t, Wrt2, Wot, b4f, b4b);
  ln_kernel<<<1024, 256, 0, stream>>>(tokens, norm_g, norm_b, t_bf);
  xz_gemm<<<3072, 256, 0, stream>>>(t_bf, Wxz_t, bx, bz, x_bf, gate_bf);
  proj_mfma<<<1024, 256, 0, stream>>>(x_bf, convf_w, convf_b, convb_w, convb_b,
                                      W4f_t, W4b_t, b4f, b4b, A_log,
                                      Af, Buf, Ctf, Ab, Bub, Ctb);
  scan2_kernel<<<1024, 256, 0, stream>>>(Af, Buf, hsf, Ab, Bub, hsb);
  final_mfma<<<2048, 256, 0, stream>>>(tokens, gate_bf, hsf, Ctf, hsb, Ctb,
                                       Wrt2, br, Wot, bo, (float*)d_out);
}